// Round 1
// baseline (424.561 us; speedup 1.0000x reference)
//
#include <hip/hip_runtime.h>

#define Nn     20000
#define IN_CH  512
#define C1     512      // H1*HID
#define H1n    8
#define HIDn   64
#define OUT_CH 16
#define En     320000
#define EPn    340000   // E + N self-loops
#define NEG    0.2f

// ---------------- GEMM1: h1[N,512] = x[N,512] @ W1[512,512]^T ----------------
#define BM 128
#define BN 128
#define BK 16

__global__ __launch_bounds__(256) void gemm1_kernel(
    const float* __restrict__ A, const float* __restrict__ B, float* __restrict__ C)
{
  __shared__ float As[BK][BM + 4];
  __shared__ float Bs[BK][BN + 4];
  int t  = threadIdx.x;
  int bm = blockIdx.x, bn = blockIdx.y;
  int lr = t >> 1;            // 0..127 row within tile
  int lk = (t & 1) * 8;       // 0 or 8
  int arow = bm * BM + lr;
  int brow = bn * BN + lr;    // always < 512
  bool aok = arow < Nn;
  const float* Ap = A + (size_t)(aok ? arow : 0) * IN_CH + lk;
  const float* Bp = B + (size_t)brow * IN_CH + lk;
  int ty = t >> 4, tx = t & 15;
  float acc[8][8] = {};

  for (int k0 = 0; k0 < IN_CH; k0 += BK) {
    float4 a0 = make_float4(0.f, 0.f, 0.f, 0.f), a1 = a0;
    if (aok) {
      a0 = *(const float4*)(Ap + k0);
      a1 = *(const float4*)(Ap + k0 + 4);
    }
    float4 b0  = *(const float4*)(Bp + k0);
    float4 b1v = *(const float4*)(Bp + k0 + 4);
    __syncthreads();
    As[lk + 0][lr] = a0.x; As[lk + 1][lr] = a0.y; As[lk + 2][lr] = a0.z; As[lk + 3][lr] = a0.w;
    As[lk + 4][lr] = a1.x; As[lk + 5][lr] = a1.y; As[lk + 6][lr] = a1.z; As[lk + 7][lr] = a1.w;
    Bs[lk + 0][lr] = b0.x; Bs[lk + 1][lr] = b0.y; Bs[lk + 2][lr] = b0.z; Bs[lk + 3][lr] = b0.w;
    Bs[lk + 4][lr] = b1v.x; Bs[lk + 5][lr] = b1v.y; Bs[lk + 6][lr] = b1v.z; Bs[lk + 7][lr] = b1v.w;
    __syncthreads();
#pragma unroll
    for (int k = 0; k < BK; k++) {
      float4 av0 = *(const float4*)&As[k][ty * 8];
      float4 av1 = *(const float4*)&As[k][ty * 8 + 4];
      float4 bv0 = *(const float4*)&Bs[k][tx * 8];
      float4 bv1 = *(const float4*)&Bs[k][tx * 8 + 4];
      float ar[8] = {av0.x, av0.y, av0.z, av0.w, av1.x, av1.y, av1.z, av1.w};
      float br[8] = {bv0.x, bv0.y, bv0.z, bv0.w, bv1.x, bv1.y, bv1.z, bv1.w};
#pragma unroll
      for (int i = 0; i < 8; i++)
#pragma unroll
        for (int j = 0; j < 8; j++) acc[i][j] = fmaf(ar[i], br[j], acc[i][j]);
    }
  }
#pragma unroll
  for (int i = 0; i < 8; i++) {
    int r = bm * BM + ty * 8 + i;
    if (r < Nn) {
      float4 o0 = {acc[i][0], acc[i][1], acc[i][2], acc[i][3]};
      float4 o1 = {acc[i][4], acc[i][5], acc[i][6], acc[i][7]};
      *(float4*)&C[(size_t)r * C1 + bn * BN + tx * 8]     = o0;
      *(float4*)&C[(size_t)r * C1 + bn * BN + tx * 8 + 4] = o1;
    }
  }
}

// ------------- per-(node,head) attention logits: a_s, a_d [N,8] -------------
__global__ __launch_bounds__(256) void logits1_kernel(
    const float* __restrict__ h1, const float* __restrict__ att_s,
    const float* __restrict__ att_d, float* __restrict__ as1, float* __restrict__ ad1)
{
  int wave = threadIdx.x >> 6, lane = threadIdx.x & 63;
  int p = blockIdx.x * 4 + wave;            // pair index n*8+h
  if (p >= Nn * H1n) return;
  int n = p >> 3, h = p & 7;
  float v = h1[(size_t)n * C1 + h * HIDn + lane];
  float s = v * att_s[h * HIDn + lane];
  float d = v * att_d[h * HIDn + lane];
#pragma unroll
  for (int off = 32; off; off >>= 1) {
    s += __shfl_xor(s, off);
    d += __shfl_xor(d, off);
  }
  if (lane == 0) { as1[p] = s; ad1[p] = d; }
}

// --------------------------- CSR build by dst -------------------------------
__global__ void hist_kernel(const int* __restrict__ ei, int* __restrict__ cnt)
{
  int e = blockIdx.x * 256 + threadIdx.x;
  if (e >= EPn) return;
  int d = (e < En) ? ei[En + e] : (e - En);
  atomicAdd(&cnt[d], 1);
}

__global__ void scan_kernel(const int* __restrict__ cnt, int* __restrict__ row)
{
  __shared__ int sm[1024];
  __shared__ int carry;
  int t = threadIdx.x;
  if (t == 0) { carry = 0; row[0] = 0; }
  __syncthreads();
  for (int base = 0; base < Nn; base += 1024) {
    int i = base + t;
    int v = (i < Nn) ? cnt[i] : 0;
    sm[t] = v;
    __syncthreads();
    for (int off = 1; off < 1024; off <<= 1) {
      int add = (t >= off) ? sm[t - off] : 0;
      __syncthreads();
      sm[t] += add;
      __syncthreads();
    }
    if (i < Nn) row[i + 1] = carry + sm[t];
    __syncthreads();
    if (t == 0) carry += sm[1023];
    __syncthreads();
  }
}

__global__ void scatter_kernel(const int* __restrict__ ei, const int* __restrict__ row,
                               int* __restrict__ cur, int* __restrict__ csr)
{
  int e = blockIdx.x * 256 + threadIdx.x;
  if (e >= EPn) return;
  int s, d;
  if (e < En) { s = ei[e]; d = ei[En + e]; }
  else        { s = e - En; d = e - En; }
  int pos = row[d] + atomicAdd(&cur[d], 1);
  csr[pos] = s;
}

// ----- layer-1 softmax + aggregate (one block per dst), fused +b1, ReLU -----
__global__ __launch_bounds__(256) void agg1_kernel(
    const int* __restrict__ row, const int* __restrict__ csr,
    const float* __restrict__ h1, const float* __restrict__ as1,
    const float* __restrict__ ad1, const float* __restrict__ b1,
    float* __restrict__ out)
{
  __shared__ int   src_s[64];
  __shared__ float alpha_s[64][8];
  int d = blockIdx.x;
  int beg = row[d], end = row[d + 1];
  int t = threadIdx.x;
  int lane = t & 63;

  float m[8], z[8], adr[8];
  if (t < 64) {
    float4 adv0 = *(const float4*)&ad1[d * 8];
    float4 adv1 = *(const float4*)&ad1[d * 8 + 4];
    adr[0] = adv0.x; adr[1] = adv0.y; adr[2] = adv0.z; adr[3] = adv0.w;
    adr[4] = adv1.x; adr[5] = adv1.y; adr[6] = adv1.z; adr[7] = adv1.w;
#pragma unroll
    for (int h = 0; h < 8; h++) m[h] = -1e30f;
    for (int e = beg + lane; e < end; e += 64) {
      int s = csr[e];
      float4 v0 = *(const float4*)&as1[s * 8];
      float4 v1 = *(const float4*)&as1[s * 8 + 4];
      float vv[8] = {v0.x, v0.y, v0.z, v0.w, v1.x, v1.y, v1.z, v1.w};
#pragma unroll
      for (int h = 0; h < 8; h++) {
        float v = vv[h] + adr[h];
        v = (v >= 0.f) ? v : NEG * v;
        m[h] = fmaxf(m[h], v);
      }
    }
#pragma unroll
    for (int h = 0; h < 8; h++)
#pragma unroll
      for (int off = 32; off; off >>= 1) m[h] = fmaxf(m[h], __shfl_xor(m[h], off));
#pragma unroll
    for (int h = 0; h < 8; h++) z[h] = 0.f;
    for (int e = beg + lane; e < end; e += 64) {
      int s = csr[e];
      float4 v0 = *(const float4*)&as1[s * 8];
      float4 v1 = *(const float4*)&as1[s * 8 + 4];
      float vv[8] = {v0.x, v0.y, v0.z, v0.w, v1.x, v1.y, v1.z, v1.w};
#pragma unroll
      for (int h = 0; h < 8; h++) {
        float v = vv[h] + adr[h];
        v = (v >= 0.f) ? v : NEG * v;
        z[h] += __expf(v - m[h]);
      }
    }
#pragma unroll
    for (int h = 0; h < 8; h++)
#pragma unroll
      for (int off = 32; off; off >>= 1) z[h] += __shfl_xor(z[h], off);
  }

  int hA = t >> 6;       // head of channel t      (0..3)
  int hB = hA + 4;       // head of channel t+256  (4..7)
  float accA = 0.f, accB = 0.f;
  for (int cbeg = beg; cbeg < end; cbeg += 64) {
    int cnt = min(64, end - cbeg);
    __syncthreads();
    if (t < 64 && lane < cnt) {
      int s = csr[cbeg + lane];
      src_s[lane] = s;
      float4 v0 = *(const float4*)&as1[s * 8];
      float4 v1 = *(const float4*)&as1[s * 8 + 4];
      float vv[8] = {v0.x, v0.y, v0.z, v0.w, v1.x, v1.y, v1.z, v1.w};
#pragma unroll
      for (int h = 0; h < 8; h++) {
        float v = vv[h] + adr[h];
        v = (v >= 0.f) ? v : NEG * v;
        alpha_s[lane][h] = __expf(v - m[h]) / z[h];
      }
    }
    __syncthreads();
    for (int i = 0; i < cnt; i++) {
      int s = src_s[i];
      const float* hp = h1 + (size_t)s * C1;
      accA = fmaf(alpha_s[i][hA], hp[t], accA);
      accB = fmaf(alpha_s[i][hB], hp[t + 256], accB);
    }
  }
  float oA = accA + b1[t];
  float oB = accB + b1[t + 256];
  out[(size_t)d * C1 + t]       = oA > 0.f ? oA : 0.f;
  out[(size_t)d * C1 + t + 256] = oB > 0.f ? oB : 0.f;
}

// --------- layer-2 transform: h2[N,16] = relu1 @ W2^T; a_s2, a_d2 -----------
__global__ __launch_bounds__(256) void l2_kernel(
    const float* __restrict__ in, const float* __restrict__ W2,
    const float* __restrict__ att_s, const float* __restrict__ att_d,
    float* __restrict__ h2, float* __restrict__ as2, float* __restrict__ ad2)
{
  __shared__ float W2s[OUT_CH * 512];
  int t = threadIdx.x;
  for (int i = t * 4; i < OUT_CH * 512; i += 1024)
    *(float4*)&W2s[i] = *(const float4*)&W2[i];
  __syncthreads();
  int wave = t >> 6, lane = t & 63;
  int n = blockIdx.x * 4 + wave;   // grid = N/4 exactly
  const float* xr = in + (size_t)n * 512;
  float acc[16] = {};
  for (int k = lane; k < 512; k += 64) {
    float xv = xr[k];
#pragma unroll
    for (int j = 0; j < 16; j++) acc[j] = fmaf(xv, W2s[j * 512 + k], acc[j]);
  }
#pragma unroll
  for (int j = 0; j < 16; j++)
#pragma unroll
    for (int off = 32; off; off >>= 1) acc[j] += __shfl_xor(acc[j], off);
  if (lane == 0) {
    float s = 0.f, dd = 0.f;
#pragma unroll
    for (int j = 0; j < 16; j++) {
      h2[(size_t)n * 16 + j] = acc[j];
      s  = fmaf(acc[j], att_s[j], s);
      dd = fmaf(acc[j], att_d[j], dd);
    }
    as2[n] = s; ad2[n] = dd;
  }
}

// ------- layer-2 softmax + aggregate (one wave per dst), fused +b2 ----------
__global__ __launch_bounds__(256) void agg2_kernel(
    const int* __restrict__ row, const int* __restrict__ csr,
    const float* __restrict__ h2, const float* __restrict__ as2,
    const float* __restrict__ ad2, const float* __restrict__ b2,
    float* __restrict__ out)
{
  int wave = threadIdx.x >> 6, lane = threadIdx.x & 63;
  int d = blockIdx.x * 4 + wave;   // grid = N/4 exactly
  int beg = row[d], end = row[d + 1];
  float add = ad2[d];

  float m = -1e30f;
  for (int e = beg + lane; e < end; e += 64) {
    float v = as2[csr[e]] + add;
    v = (v >= 0.f) ? v : NEG * v;
    m = fmaxf(m, v);
  }
#pragma unroll
  for (int off = 32; off; off >>= 1) m = fmaxf(m, __shfl_xor(m, off));
  float z = 0.f;
  for (int e = beg + lane; e < end; e += 64) {
    float v = as2[csr[e]] + add;
    v = (v >= 0.f) ? v : NEG * v;
    z += __expf(v - m);
  }
#pragma unroll
  for (int off = 32; off; off >>= 1) z += __shfl_xor(z, off);

  int c = lane & 15;
  float acc = 0.f;
  for (int e = beg + (lane >> 4); e < end; e += 4) {
    int s = csr[e];
    float v = as2[s] + add;
    v = (v >= 0.f) ? v : NEG * v;
    float al = __expf(v - m) / z;
    acc = fmaf(al, h2[(size_t)s * 16 + c], acc);
  }
  acc += __shfl_xor(acc, 16);
  acc += __shfl_xor(acc, 32);
  if (lane < 16) out[(size_t)d * 16 + lane] = acc + b2[lane];
}

extern "C" void kernel_launch(void* const* d_in, const int* in_sizes, int n_in,
                              void* d_out, int out_size, void* d_ws, size_t ws_size,
                              hipStream_t stream)
{
  const float* x    = (const float*)d_in[0];
  const int*   ei   = (const int*)d_in[1];
  const float* W1   = (const float*)d_in[2];
  const float* asv1 = (const float*)d_in[3];
  const float* adv1 = (const float*)d_in[4];
  const float* b1   = (const float*)d_in[5];
  const float* W2   = (const float*)d_in[6];
  const float* asv2 = (const float*)d_in[7];
  const float* adv2 = (const float*)d_in[8];
  const float* b2   = (const float*)d_in[9];
  float* out = (float*)d_out;

  float* ws_f  = (float*)d_ws;
  float* h1    = ws_f;                         // N*512
  float* relu1 = h1 + (size_t)Nn * C1;         // N*512
  float* as1   = relu1 + (size_t)Nn * C1;      // N*8
  float* ad1   = as1 + (size_t)Nn * H1n;       // N*8
  float* h2    = ad1 + (size_t)Nn * H1n;       // N*16
  float* as2   = h2 + (size_t)Nn * OUT_CH;     // N
  float* ad2   = as2 + Nn;                     // N
  int* cnt  = (int*)(ad2 + Nn);                // N
  int* rowp = cnt + Nn;                        // N+1
  int* cur  = rowp + Nn + 1;                   // N
  int* csr  = cur + Nn;                        // E+N

  hipMemsetAsync(cnt, 0, Nn * sizeof(int), stream);
  hipMemsetAsync(cur, 0, Nn * sizeof(int), stream);

  dim3 g1(157, 4);
  gemm1_kernel<<<g1, 256, 0, stream>>>(x, W1, h1);
  logits1_kernel<<<(Nn * H1n) / 4, 256, 0, stream>>>(h1, asv1, adv1, as1, ad1);
  hist_kernel<<<(EPn + 255) / 256, 256, 0, stream>>>(ei, cnt);
  scan_kernel<<<1, 1024, 0, stream>>>(cnt, rowp);
  scatter_kernel<<<(EPn + 255) / 256, 256, 0, stream>>>(ei, rowp, cur, csr);
  agg1_kernel<<<Nn, 256, 0, stream>>>(rowp, csr, h1, as1, ad1, b1, relu1);
  l2_kernel<<<Nn / 4, 256, 0, stream>>>(relu1, W2, asv2, adv2, h2, as2, ad2);
  agg2_kernel<<<Nn / 4, 256, 0, stream>>>(rowp, csr, h2, as2, ad2, b2, out);
}

// Round 2
// 340.265 us; speedup vs baseline: 1.2477x; 1.2477x over previous
//
#include <hip/hip_runtime.h>

#define Nn     20000
#define IN_CH  512
#define C1     512      // H1*HID
#define H1n    8
#define HIDn   64
#define OUT_CH 16
#define En     320000
#define EPn    340000   // E + N self-loops
#define NEG    0.2f

typedef __attribute__((ext_vector_type(8))) short bf16x8;
typedef __attribute__((ext_vector_type(4))) float f32x4;

// ---------------- fp32 -> (hi, lo) bf16 split, RNE both terms ----------------
__device__ inline unsigned short bf16_rne(float f) {
  unsigned int u = __float_as_uint(f);
  return (unsigned short)((u + 0x7fffu + ((u >> 16) & 1u)) >> 16);
}

__global__ __launch_bounds__(256) void split_kernel(
    const float* __restrict__ in, unsigned short* __restrict__ hi,
    unsigned short* __restrict__ lo, int n8)
{
  int i = blockIdx.x * 256 + threadIdx.x;
  if (i >= n8) return;
  float4 f0 = ((const float4*)in)[i * 2];
  float4 f1 = ((const float4*)in)[i * 2 + 1];
  float f[8] = {f0.x, f0.y, f0.z, f0.w, f1.x, f1.y, f1.z, f1.w};
  unsigned short h[8], l[8];
#pragma unroll
  for (int j = 0; j < 8; j++) {
    unsigned short hb = bf16_rne(f[j]);
    h[j] = hb;
    float hf = __uint_as_float(((unsigned int)hb) << 16);
    l[j] = bf16_rne(f[j] - hf);
  }
  ushort4 hv0 = {h[0], h[1], h[2], h[3]}, hv1 = {h[4], h[5], h[6], h[7]};
  ushort4 lv0 = {l[0], l[1], l[2], l[3]}, lv1 = {l[4], l[5], l[6], l[7]};
  ((ushort4*)hi)[i * 2] = hv0; ((ushort4*)hi)[i * 2 + 1] = hv1;
  ((ushort4*)lo)[i * 2] = lv0; ((ushort4*)lo)[i * 2 + 1] = lv1;
}

// ------ GEMM1 (split-bf16 MFMA): h1[N,512] = x[N,512] @ W1[512,512]^T -------
#define GLL(gp, lp) __builtin_amdgcn_global_load_lds( \
    (const __attribute__((address_space(1))) void*)(gp), \
    (__attribute__((address_space(3))) void*)(lp), 16, 0, 0)

__global__ __launch_bounds__(256, 2) void gemm1_mfma(
    const unsigned short* __restrict__ Ahi, const unsigned short* __restrict__ Alo,
    const unsigned short* __restrict__ Bhi, const unsigned short* __restrict__ Blo,
    float* __restrict__ C)
{
  __shared__ unsigned short sAhi[128 * 32], sAlo[128 * 32];
  __shared__ unsigned short sBhi[128 * 32], sBlo[128 * 32];
  int t = threadIdx.x;
  int bm = blockIdx.x, bn = blockIdx.y;
  int lane = t & 63, w = t >> 6;

  // staging: 512 chunks of 16B (8 bf16) per tile; thread handles chunks c0, c1
  int c0 = w * 128 + lane;
  int c1 = c0 + 64;
  int cb0 = w * 128, cb1 = w * 128 + 64;       // wave-uniform LDS base chunks
  int ar0 = bm * 128 + (c0 >> 2); if (ar0 > Nn - 1) ar0 = Nn - 1;
  int ar1 = bm * 128 + (c1 >> 2); if (ar1 > Nn - 1) ar1 = Nn - 1;
  int br0 = bn * 128 + (c0 >> 2);
  int br1 = bn * 128 + (c1 >> 2);
  size_t offA0 = (size_t)ar0 * IN_CH + (c0 & 3) * 8;
  size_t offA1 = (size_t)ar1 * IN_CH + (c1 & 3) * 8;
  size_t offB0 = (size_t)br0 * IN_CH + (c0 & 3) * 8;
  size_t offB1 = (size_t)br1 * IN_CH + (c1 & 3) * 8;

  int wm = (w >> 1) * 64, wn = (w & 1) * 64;
  int lr = lane & 15, kb = lane >> 4;

  f32x4 acc[4][4] = {};

  for (int k0 = 0; k0 < IN_CH; k0 += 32) {
    __syncthreads();                      // prev iter's LDS reads done
    GLL(Ahi + offA0 + k0, sAhi + cb0 * 8);
    GLL(Ahi + offA1 + k0, sAhi + cb1 * 8);
    GLL(Alo + offA0 + k0, sAlo + cb0 * 8);
    GLL(Alo + offA1 + k0, sAlo + cb1 * 8);
    GLL(Bhi + offB0 + k0, sBhi + cb0 * 8);
    GLL(Bhi + offB1 + k0, sBhi + cb1 * 8);
    GLL(Blo + offB0 + k0, sBlo + cb0 * 8);
    GLL(Blo + offB1 + k0, sBlo + cb1 * 8);
    __syncthreads();                      // loads landed (vmcnt(0) drained)

    bf16x8 ah[4], al[4], bh[4], bl[4];
#pragma unroll
    for (int i = 0; i < 4; i++) {
      int ra = (wm + i * 16 + lr) * 32 + kb * 8;
      ah[i] = *(const bf16x8*)&sAhi[ra];
      al[i] = *(const bf16x8*)&sAlo[ra];
      int rb = (wn + i * 16 + lr) * 32 + kb * 8;
      bh[i] = *(const bf16x8*)&sBhi[rb];
      bl[i] = *(const bf16x8*)&sBlo[rb];
    }
#pragma unroll
    for (int i = 0; i < 4; i++)
#pragma unroll
      for (int j = 0; j < 4; j++) {
        acc[i][j] = __builtin_amdgcn_mfma_f32_16x16x32_bf16(ah[i], bh[j], acc[i][j], 0, 0, 0);
        acc[i][j] = __builtin_amdgcn_mfma_f32_16x16x32_bf16(ah[i], bl[j], acc[i][j], 0, 0, 0);
        acc[i][j] = __builtin_amdgcn_mfma_f32_16x16x32_bf16(al[i], bh[j], acc[i][j], 0, 0, 0);
      }
  }

  int lq = lane >> 4;
#pragma unroll
  for (int i = 0; i < 4; i++) {
    int r0 = bm * 128 + wm + i * 16 + lq * 4;
#pragma unroll
    for (int j = 0; j < 4; j++) {
      int cc = bn * 128 + wn + j * 16 + lr;
#pragma unroll
      for (int q = 0; q < 4; q++) {
        int r = r0 + q;
        if (r < Nn) C[(size_t)r * C1 + cc] = acc[i][j][q];
      }
    }
  }
}

// ------------- per-(node,head) attention logits: a_s, a_d [N,8] -------------
__global__ __launch_bounds__(256) void logits1_kernel(
    const float* __restrict__ h1, const float* __restrict__ att_s,
    const float* __restrict__ att_d, float* __restrict__ as1, float* __restrict__ ad1)
{
  int wave = threadIdx.x >> 6, lane = threadIdx.x & 63;
  int p = blockIdx.x * 4 + wave;            // pair index n*8+h
  if (p >= Nn * H1n) return;
  int n = p >> 3, h = p & 7;
  float v = h1[(size_t)n * C1 + h * HIDn + lane];
  float s = v * att_s[h * HIDn + lane];
  float d = v * att_d[h * HIDn + lane];
#pragma unroll
  for (int off = 32; off; off >>= 1) {
    s += __shfl_xor(s, off);
    d += __shfl_xor(d, off);
  }
  if (lane == 0) { as1[p] = s; ad1[p] = d; }
}

// --------------------------- CSR build by dst -------------------------------
__global__ void hist_kernel(const int* __restrict__ ei, int* __restrict__ cnt)
{
  int e = blockIdx.x * 256 + threadIdx.x;
  if (e >= EPn) return;
  int d = (e < En) ? ei[En + e] : (e - En);
  atomicAdd(&cnt[d], 1);
}

__global__ void scan_kernel(const int* __restrict__ cnt, int* __restrict__ row)
{
  __shared__ int sm[1024];
  __shared__ int carry;
  int t = threadIdx.x;
  if (t == 0) { carry = 0; row[0] = 0; }
  __syncthreads();
  for (int base = 0; base < Nn; base += 1024) {
    int i = base + t;
    int v = (i < Nn) ? cnt[i] : 0;
    sm[t] = v;
    __syncthreads();
    for (int off = 1; off < 1024; off <<= 1) {
      int add = (t >= off) ? sm[t - off] : 0;
      __syncthreads();
      sm[t] += add;
      __syncthreads();
    }
    if (i < Nn) row[i + 1] = carry + sm[t];
    __syncthreads();
    if (t == 0) carry += sm[1023];
    __syncthreads();
  }
}

__global__ void scatter_kernel(const int* __restrict__ ei, const int* __restrict__ row,
                               int* __restrict__ cur, int* __restrict__ csr)
{
  int e = blockIdx.x * 256 + threadIdx.x;
  if (e >= EPn) return;
  int s, d;
  if (e < En) { s = ei[e]; d = ei[En + e]; }
  else        { s = e - En; d = e - En; }
  int pos = row[d] + atomicAdd(&cur[d], 1);
  csr[pos] = s;
}

// ----- layer-1 softmax + aggregate (one block per dst), fused +b1, ReLU -----
__global__ __launch_bounds__(256) void agg1_kernel(
    const int* __restrict__ row, const int* __restrict__ csr,
    const float* __restrict__ h1, const float* __restrict__ as1,
    const float* __restrict__ ad1, const float* __restrict__ b1,
    float* __restrict__ out)
{
  __shared__ int   src_s[64];
  __shared__ float alpha_s[64][8];
  int d = blockIdx.x;
  int beg = row[d], end = row[d + 1];
  int t = threadIdx.x;
  int lane = t & 63;

  float m[8], z[8], adr[8];
  if (t < 64) {
    float4 adv0 = *(const float4*)&ad1[d * 8];
    float4 adv1 = *(const float4*)&ad1[d * 8 + 4];
    adr[0] = adv0.x; adr[1] = adv0.y; adr[2] = adv0.z; adr[3] = adv0.w;
    adr[4] = adv1.x; adr[5] = adv1.y; adr[6] = adv1.z; adr[7] = adv1.w;
#pragma unroll
    for (int h = 0; h < 8; h++) m[h] = -1e30f;
    for (int e = beg + lane; e < end; e += 64) {
      int s = csr[e];
      float4 v0 = *(const float4*)&as1[s * 8];
      float4 v1 = *(const float4*)&as1[s * 8 + 4];
      float vv[8] = {v0.x, v0.y, v0.z, v0.w, v1.x, v1.y, v1.z, v1.w};
#pragma unroll
      for (int h = 0; h < 8; h++) {
        float v = vv[h] + adr[h];
        v = (v >= 0.f) ? v : NEG * v;
        m[h] = fmaxf(m[h], v);
      }
    }
#pragma unroll
    for (int h = 0; h < 8; h++)
#pragma unroll
      for (int off = 32; off; off >>= 1) m[h] = fmaxf(m[h], __shfl_xor(m[h], off));
#pragma unroll
    for (int h = 0; h < 8; h++) z[h] = 0.f;
    for (int e = beg + lane; e < end; e += 64) {
      int s = csr[e];
      float4 v0 = *(const float4*)&as1[s * 8];
      float4 v1 = *(const float4*)&as1[s * 8 + 4];
      float vv[8] = {v0.x, v0.y, v0.z, v0.w, v1.x, v1.y, v1.z, v1.w};
#pragma unroll
      for (int h = 0; h < 8; h++) {
        float v = vv[h] + adr[h];
        v = (v >= 0.f) ? v : NEG * v;
        z[h] += __expf(v - m[h]);
      }
    }
#pragma unroll
    for (int h = 0; h < 8; h++)
#pragma unroll
      for (int off = 32; off; off >>= 1) z[h] += __shfl_xor(z[h], off);
  }

  int hA = t >> 6;       // head of channel t      (0..3)
  int hB = hA + 4;       // head of channel t+256  (4..7)
  float accA = 0.f, accB = 0.f;
  for (int cbeg = beg; cbeg < end; cbeg += 64) {
    int cnt = min(64, end - cbeg);
    __syncthreads();
    if (t < 64 && lane < cnt) {
      int s = csr[cbeg + lane];
      src_s[lane] = s;
      float4 v0 = *(const float4*)&as1[s * 8];
      float4 v1 = *(const float4*)&as1[s * 8 + 4];
      float vv[8] = {v0.x, v0.y, v0.z, v0.w, v1.x, v1.y, v1.z, v1.w};
#pragma unroll
      for (int h = 0; h < 8; h++) {
        float v = vv[h] + adr[h];
        v = (v >= 0.f) ? v : NEG * v;
        alpha_s[lane][h] = __expf(v - m[h]) / z[h];
      }
    }
    __syncthreads();
    for (int i = 0; i < cnt; i++) {
      int s = src_s[i];
      const float* hp = h1 + (size_t)s * C1;
      accA = fmaf(alpha_s[i][hA], hp[t], accA);
      accB = fmaf(alpha_s[i][hB], hp[t + 256], accB);
    }
  }
  float oA = accA + b1[t];
  float oB = accB + b1[t + 256];
  out[(size_t)d * C1 + t]       = oA > 0.f ? oA : 0.f;
  out[(size_t)d * C1 + t + 256] = oB > 0.f ? oB : 0.f;
}

// --------- layer-2 transform: h2[N,16] = relu1 @ W2^T; a_s2, a_d2 -----------
__global__ __launch_bounds__(256) void l2_kernel(
    const float* __restrict__ in, const float* __restrict__ W2,
    const float* __restrict__ att_s, const float* __restrict__ att_d,
    float* __restrict__ h2, float* __restrict__ as2, float* __restrict__ ad2)
{
  __shared__ float W2s[OUT_CH * 512];
  int t = threadIdx.x;
  for (int i = t * 4; i < OUT_CH * 512; i += 1024)
    *(float4*)&W2s[i] = *(const float4*)&W2[i];
  __syncthreads();
  int wave = t >> 6, lane = t & 63;
  int n = blockIdx.x * 4 + wave;   // grid = N/4 exactly
  const float* xr = in + (size_t)n * 512;
  float acc[16] = {};
  for (int k = lane; k < 512; k += 64) {
    float xv = xr[k];
#pragma unroll
    for (int j = 0; j < 16; j++) acc[j] = fmaf(xv, W2s[j * 512 + k], acc[j]);
  }
#pragma unroll
  for (int j = 0; j < 16; j++)
#pragma unroll
    for (int off = 32; off; off >>= 1) acc[j] += __shfl_xor(acc[j], off);
  if (lane == 0) {
    float s = 0.f, dd = 0.f;
#pragma unroll
    for (int j = 0; j < 16; j++) {
      h2[(size_t)n * 16 + j] = acc[j];
      s  = fmaf(acc[j], att_s[j], s);
      dd = fmaf(acc[j], att_d[j], dd);
    }
    as2[n] = s; ad2[n] = dd;
  }
}

// ------- layer-2 softmax + aggregate (one wave per dst), fused +b2 ----------
__global__ __launch_bounds__(256) void agg2_kernel(
    const int* __restrict__ row, const int* __restrict__ csr,
    const float* __restrict__ h2, const float* __restrict__ as2,
    const float* __restrict__ ad2, const float* __restrict__ b2,
    float* __restrict__ out)
{
  int wave = threadIdx.x >> 6, lane = threadIdx.x & 63;
  int d = blockIdx.x * 4 + wave;   // grid = N/4 exactly
  int beg = row[d], end = row[d + 1];
  float add = ad2[d];

  float m = -1e30f;
  for (int e = beg + lane; e < end; e += 64) {
    float v = as2[csr[e]] + add;
    v = (v >= 0.f) ? v : NEG * v;
    m = fmaxf(m, v);
  }
#pragma unroll
  for (int off = 32; off; off >>= 1) m = fmaxf(m, __shfl_xor(m, off));
  float z = 0.f;
  for (int e = beg + lane; e < end; e += 64) {
    float v = as2[csr[e]] + add;
    v = (v >= 0.f) ? v : NEG * v;
    z += __expf(v - m);
  }
#pragma unroll
  for (int off = 32; off; off >>= 1) z += __shfl_xor(z, off);

  int c = lane & 15;
  float acc = 0.f;
  for (int e = beg + (lane >> 4); e < end; e += 4) {
    int s = csr[e];
    float v = as2[s] + add;
    v = (v >= 0.f) ? v : NEG * v;
    float al = __expf(v - m) / z;
    acc = fmaf(al, h2[(size_t)s * 16 + c], acc);
  }
  acc += __shfl_xor(acc, 16);
  acc += __shfl_xor(acc, 32);
  if (lane < 16) out[(size_t)d * 16 + lane] = acc + b2[lane];
}

extern "C" void kernel_launch(void* const* d_in, const int* in_sizes, int n_in,
                              void* d_out, int out_size, void* d_ws, size_t ws_size,
                              hipStream_t stream)
{
  const float* x    = (const float*)d_in[0];
  const int*   ei   = (const int*)d_in[1];
  const float* W1   = (const float*)d_in[2];
  const float* asv1 = (const float*)d_in[3];
  const float* adv1 = (const float*)d_in[4];
  const float* b1   = (const float*)d_in[5];
  const float* W2   = (const float*)d_in[6];
  const float* asv2 = (const float*)d_in[7];
  const float* adv2 = (const float*)d_in[8];
  const float* b2   = (const float*)d_in[9];
  float* out = (float*)d_out;

  // workspace layout (16B-aligned regions)
  float* ws_f  = (float*)d_ws;
  float* h1    = ws_f;                         // N*512 f32
  float* relu1 = h1 + (size_t)Nn * C1;         // N*512 f32  (aliased: x_hi/x_lo before agg1)
  float* as1   = relu1 + (size_t)Nn * C1;      // N*8
  float* ad1   = as1 + (size_t)Nn * H1n;       // N*8
  float* h2    = ad1 + (size_t)Nn * H1n;       // N*16
  float* as2   = h2 + (size_t)Nn * OUT_CH;     // N
  float* ad2   = as2 + Nn;                     // N
  int* csr  = (int*)(ad2 + Nn);                // E+N  (aliased: W_hi/W_lo before scatter)
  int* cnt  = csr + EPn;                       // N
  int* rowp = cnt + Nn;                        // N+1
  int* cur  = rowp + Nn + 1;                   // N

  // aliases (consumed before their regions are overwritten)
  unsigned short* x_hi = (unsigned short*)relu1;             // N*512 bf16
  unsigned short* x_lo = x_hi + (size_t)Nn * IN_CH;          // N*512 bf16
  unsigned short* w_hi = (unsigned short*)csr;               // 512*512 bf16
  unsigned short* w_lo = w_hi + (size_t)C1 * IN_CH;          // 512*512 bf16

  hipMemsetAsync(cnt, 0, Nn * sizeof(int), stream);
  hipMemsetAsync(cur, 0, Nn * sizeof(int), stream);

  split_kernel<<<(Nn * IN_CH / 8 + 255) / 256, 256, 0, stream>>>(x, x_hi, x_lo, Nn * IN_CH / 8);
  split_kernel<<<(C1 * IN_CH / 8 + 255) / 256, 256, 0, stream>>>(W1, w_hi, w_lo, C1 * IN_CH / 8);

  dim3 g1(157, 4);
  gemm1_mfma<<<g1, 256, 0, stream>>>(x_hi, x_lo, w_hi, w_lo, h1);

  logits1_kernel<<<(Nn * H1n) / 4, 256, 0, stream>>>(h1, asv1, adv1, as1, ad1);
  hist_kernel<<<(EPn + 255) / 256, 256, 0, stream>>>(ei, cnt);
  scan_kernel<<<1, 1024, 0, stream>>>(cnt, rowp);
  scatter_kernel<<<(EPn + 255) / 256, 256, 0, stream>>>(ei, rowp, cur, csr);  // overwrites w_hi/w_lo (gemm done)
  agg1_kernel<<<Nn, 256, 0, stream>>>(rowp, csr, h1, as1, ad1, b1, relu1);    // overwrites x_hi/x_lo (gemm done)
  l2_kernel<<<Nn / 4, 256, 0, stream>>>(relu1, W2, asv2, adv2, h2, as2, ad2);
  agg2_kernel<<<Nn / 4, 256, 0, stream>>>(rowp, csr, h2, as2, ad2, b2, out);
}

// Round 4
// 299.569 us; speedup vs baseline: 1.4172x; 1.1359x over previous
//
#include <hip/hip_runtime.h>

#define Nn     20000
#define IN_CH  512
#define C1     512      // H1*HID
#define H1n    8
#define HIDn   64
#define OUT_CH 16
#define En     320000
#define EPn    340000   // E + N self-loops
#define NEG    0.2f

typedef __attribute__((ext_vector_type(8))) short bf16x8;
typedef __attribute__((ext_vector_type(4))) float f32x4;

// ---------------- fp32 -> (hi, lo) bf16 split, RNE both terms ----------------
__device__ inline unsigned short bf16_rne(float f) {
  unsigned int u = __float_as_uint(f);
  return (unsigned short)((u + 0x7fffu + ((u >> 16) & 1u)) >> 16);
}
__device__ inline float bf16_f(unsigned short u) {
  return __uint_as_float(((unsigned int)u) << 16);
}

__global__ __launch_bounds__(256) void split_kernel(
    const float* __restrict__ in, unsigned short* __restrict__ hi,
    unsigned short* __restrict__ lo, int n8)
{
  int i = blockIdx.x * 256 + threadIdx.x;
  if (i >= n8) return;
  float4 f0 = ((const float4*)in)[i * 2];
  float4 f1 = ((const float4*)in)[i * 2 + 1];
  float f[8] = {f0.x, f0.y, f0.z, f0.w, f1.x, f1.y, f1.z, f1.w};
  unsigned short h[8], l[8];
#pragma unroll
  for (int j = 0; j < 8; j++) {
    unsigned short hb = bf16_rne(f[j]);
    h[j] = hb;
    l[j] = bf16_rne(f[j] - bf16_f(hb));
  }
  ushort4 hv0 = {h[0], h[1], h[2], h[3]}, hv1 = {h[4], h[5], h[6], h[7]};
  ushort4 lv0 = {l[0], l[1], l[2], l[3]}, lv1 = {l[4], l[5], l[6], l[7]};
  ((ushort4*)hi)[i * 2] = hv0; ((ushort4*)hi)[i * 2 + 1] = hv1;
  ((ushort4*)lo)[i * 2] = lv0; ((ushort4*)lo)[i * 2 + 1] = lv1;
}

// ------ GEMM1 (split-bf16 MFMA): h1b[N,512](bf16) = x @ W1^T ----------------
#define GLL(gp, lp) __builtin_amdgcn_global_load_lds( \
    (const __attribute__((address_space(1))) void*)(gp), \
    (__attribute__((address_space(3))) void*)(lp), 16, 0, 0)

// involutive chunk swizzle: spreads 64B-stride rows across all 8 bank groups
#define SWZ(c) ((c) ^ (((c) >> 3) & 3))

__global__ __launch_bounds__(256, 2) void gemm1_mfma(
    const unsigned short* __restrict__ Ahi, const unsigned short* __restrict__ Alo,
    const unsigned short* __restrict__ Bhi, const unsigned short* __restrict__ Blo,
    unsigned short* __restrict__ Cb)
{
  __shared__ unsigned short sAhi[128 * 32], sAlo[128 * 32];
  __shared__ unsigned short sBhi[128 * 32], sBlo[128 * 32];
  int t = threadIdx.x;
  int bm = blockIdx.x, bn = blockIdx.y;
  int lane = t & 63, w = t >> 6;

  // staging: 512 16B-chunks per tile; LDS slot q holds tile-chunk SWZ(q)
  int slot0 = w * 128 + lane;
  int slot1 = slot0 + 64;
  int cb0 = w * 128, cb1 = w * 128 + 64;     // wave-uniform LDS base chunks
  int cs0 = SWZ(slot0), cs1 = SWZ(slot1);    // tile-chunk fetched by this lane
  int ar0 = bm * 128 + (cs0 >> 2); if (ar0 > Nn - 1) ar0 = Nn - 1;
  int ar1 = bm * 128 + (cs1 >> 2); if (ar1 > Nn - 1) ar1 = Nn - 1;
  int br0 = bn * 128 + (cs0 >> 2);
  int br1 = bn * 128 + (cs1 >> 2);
  size_t offA0 = (size_t)ar0 * IN_CH + (cs0 & 3) * 8;
  size_t offA1 = (size_t)ar1 * IN_CH + (cs1 & 3) * 8;
  size_t offB0 = (size_t)br0 * IN_CH + (cs0 & 3) * 8;
  size_t offB1 = (size_t)br1 * IN_CH + (cs1 & 3) * 8;

  int wm = (w >> 1) * 64, wn = (w & 1) * 64;
  int lr = lane & 15, kb = lane >> 4;

  f32x4 acc[4][4] = {};

  for (int k0 = 0; k0 < IN_CH; k0 += 32) {
    __syncthreads();                      // prev iter's LDS reads done
    GLL(Ahi + offA0 + k0, sAhi + cb0 * 8);
    GLL(Ahi + offA1 + k0, sAhi + cb1 * 8);
    GLL(Alo + offA0 + k0, sAlo + cb0 * 8);
    GLL(Alo + offA1 + k0, sAlo + cb1 * 8);
    GLL(Bhi + offB0 + k0, sBhi + cb0 * 8);
    GLL(Bhi + offB1 + k0, sBhi + cb1 * 8);
    GLL(Blo + offB0 + k0, sBlo + cb0 * 8);
    GLL(Blo + offB1 + k0, sBlo + cb1 * 8);
    __syncthreads();                      // loads landed

    bf16x8 ah[4], al[4], bh[4], bl[4];
#pragma unroll
    for (int i = 0; i < 4; i++) {
      int rca = (wm + i * 16 + lr) * 4 + kb;
      int sca = SWZ(rca);
      ah[i] = *(const bf16x8*)&sAhi[sca * 8];
      al[i] = *(const bf16x8*)&sAlo[sca * 8];
      int rcb = (wn + i * 16 + lr) * 4 + kb;
      int scb = SWZ(rcb);
      bh[i] = *(const bf16x8*)&sBhi[scb * 8];
      bl[i] = *(const bf16x8*)&sBlo[scb * 8];
    }
#pragma unroll
    for (int i = 0; i < 4; i++)
#pragma unroll
      for (int j = 0; j < 4; j++) {
        acc[i][j] = __builtin_amdgcn_mfma_f32_16x16x32_bf16(ah[i], bh[j], acc[i][j], 0, 0, 0);
        acc[i][j] = __builtin_amdgcn_mfma_f32_16x16x32_bf16(ah[i], bl[j], acc[i][j], 0, 0, 0);
        acc[i][j] = __builtin_amdgcn_mfma_f32_16x16x32_bf16(al[i], bh[j], acc[i][j], 0, 0, 0);
      }
  }

  int lq = lane >> 4;
#pragma unroll
  for (int i = 0; i < 4; i++) {
    int r0 = bm * 128 + wm + i * 16 + lq * 4;
#pragma unroll
    for (int j = 0; j < 4; j++) {
      int cc = bn * 128 + wn + j * 16 + lr;
#pragma unroll
      for (int q = 0; q < 4; q++) {
        int r = r0 + q;
        if (r < Nn) Cb[(size_t)r * C1 + cc] = bf16_rne(acc[i][j][q]);
      }
    }
  }
}

// ------------- per-(node,head) attention logits from bf16 h1 ----------------
__global__ __launch_bounds__(256) void logits1_kernel(
    const unsigned short* __restrict__ h1b, const float* __restrict__ att_s,
    const float* __restrict__ att_d, float* __restrict__ as1, float* __restrict__ ad1)
{
  int wave = threadIdx.x >> 6, lane = threadIdx.x & 63;
  int p = blockIdx.x * 4 + wave;            // pair index n*8+h
  if (p >= Nn * H1n) return;
  int n = p >> 3, h = p & 7;
  float v = bf16_f(h1b[(size_t)n * C1 + h * HIDn + lane]);
  float s = v * att_s[h * HIDn + lane];
  float d = v * att_d[h * HIDn + lane];
#pragma unroll
  for (int off = 32; off; off >>= 1) {
    s += __shfl_xor(s, off);
    d += __shfl_xor(d, off);
  }
  if (lane == 0) { as1[p] = s; ad1[p] = d; }
}

// --------------------------- CSR build by dst -------------------------------
__global__ void hist_kernel(const int* __restrict__ ei, int* __restrict__ cnt)
{
  int e = blockIdx.x * 256 + threadIdx.x;
  if (e >= EPn) return;
  int d = (e < En) ? ei[En + e] : (e - En);
  atomicAdd(&cnt[d], 1);
}

__global__ __launch_bounds__(1024) void scan_kernel(
    const int* __restrict__ cnt, int* __restrict__ row)
{
  __shared__ int wsum[16];
  int t = threadIdx.x;
  int base = t * 20;
  int v[20];
  int s = 0;
#pragma unroll
  for (int j = 0; j < 20; j++) {
    int i = base + j;
    int c = (i < Nn) ? cnt[i] : 0;
    v[j] = s;
    s += c;
  }
  int lane = t & 63, w = t >> 6;
  int incl = s;
#pragma unroll
  for (int off = 1; off < 64; off <<= 1) {
    int o = __shfl_up(incl, off);
    if (lane >= off) incl += o;
  }
  if (lane == 63) wsum[w] = incl;
  __syncthreads();
  if (w == 0) {
    int ws = (lane < 16) ? wsum[lane] : 0;
#pragma unroll
    for (int off = 1; off < 16; off <<= 1) {
      int o = __shfl_up(ws, off);
      if (lane >= off) ws += o;
    }
    if (lane < 16) wsum[lane] = ws;
  }
  __syncthreads();
  int excl = ((w > 0) ? wsum[w - 1] : 0) + incl - s;
#pragma unroll
  for (int j = 0; j < 20; j++) {
    int i = base + j;
    if (i < Nn) row[i] = excl + v[j];
  }
  if (t == 0) row[Nn] = EPn;
}

__global__ void scatter_kernel(const int* __restrict__ ei, const int* __restrict__ row,
                               int* __restrict__ cur, int* __restrict__ csr)
{
  int e = blockIdx.x * 256 + threadIdx.x;
  if (e >= EPn) return;
  int s, d;
  if (e < En) { s = ei[e]; d = ei[En + e]; }
  else        { s = e - En; d = e - En; }
  int pos = row[d] + atomicAdd(&cur[d], 1);
  csr[pos] = s;
}

// ----- layer-1 softmax + aggregate: LDS-free, barrier-free ------------------
// wave w owns heads {2w, 2w+1}; thread t owns channels {2t, 2t+1} whose head
// is t>>5 = 2w + (lane>>5) -- exactly the heads wave w computed m/z for.
__global__ __launch_bounds__(256) void agg1_kernel(
    const int* __restrict__ row, const int* __restrict__ csr,
    const unsigned short* __restrict__ h1b, const float* __restrict__ as1,
    const float* __restrict__ adv, const float* __restrict__ b1,
    float* __restrict__ out)
{
  int d = blockIdx.x;
  int beg = row[d], end = row[d + 1];
  int t = threadIdx.x, lane = t & 63, w = t >> 6;
  int hA = 2 * w, hB = 2 * w + 1;
  float adA = adv[d * 8 + hA], adB = adv[d * 8 + hB];

  // pass 1: per-head max (lanes stride edges)
  float mA = -1e30f, mB = -1e30f;
  for (int e = beg + lane; e < end; e += 64) {
    int s = csr[e];
    float vA = as1[s * 8 + hA] + adA; vA = vA >= 0.f ? vA : NEG * vA;
    float vB = as1[s * 8 + hB] + adB; vB = vB >= 0.f ? vB : NEG * vB;
    mA = fmaxf(mA, vA); mB = fmaxf(mB, vB);
  }
#pragma unroll
  for (int off = 32; off; off >>= 1) {
    mA = fmaxf(mA, __shfl_xor(mA, off));
    mB = fmaxf(mB, __shfl_xor(mB, off));
  }
  // pass 2: per-head denom
  float zA = 0.f, zB = 0.f;
  for (int e = beg + lane; e < end; e += 64) {
    int s = csr[e];
    float vA = as1[s * 8 + hA] + adA; vA = vA >= 0.f ? vA : NEG * vA;
    float vB = as1[s * 8 + hB] + adB; vB = vB >= 0.f ? vB : NEG * vB;
    zA += __expf(vA - mA); zB += __expf(vB - mB);
  }
#pragma unroll
  for (int off = 32; off; off >>= 1) {
    zA += __shfl_xor(zA, off);
    zB += __shfl_xor(zB, off);
  }

  // per-half-wave head selection (head of channels 2t,2t+1)
  int hi2 = lane >> 5;                       // 0: head hA, 1: head hB
  float mH  = hi2 ? mB : mA;
  float rzH = 1.f / (hi2 ? zB : zA);
  float adH = hi2 ? adB : adA;
  int   hh  = 2 * w + hi2;

  // pass 3: aggregate (alpha recomputed from broadcast loads; no LDS)
  int ch = 2 * t;
  float acc0 = 0.f, acc1 = 0.f;
  for (int e = beg; e < end; e++) {
    int s = csr[e];                          // wave-uniform broadcast load
    float v = as1[s * 8 + hh] + adH;         // 2 broadcast addrs per wave
    v = (v >= 0.f) ? v : NEG * v;
    float al = __expf(v - mH) * rzH;
    unsigned int u = *(const unsigned int*)&h1b[(size_t)s * C1 + ch];
    acc0 = fmaf(al, __uint_as_float(u << 16), acc0);
    acc1 = fmaf(al, __uint_as_float(u & 0xffff0000u), acc1);
  }
  float o0 = acc0 + b1[ch], o1 = acc1 + b1[ch + 1];
  float2 o = {o0 > 0.f ? o0 : 0.f, o1 > 0.f ? o1 : 0.f};
  *(float2*)&out[(size_t)d * C1 + ch] = o;
}

// --------- layer-2 transform: h2[N,16] = relu1 @ W2^T; a_s2, a_d2 -----------
__global__ __launch_bounds__(256) void l2_kernel(
    const float* __restrict__ in, const float* __restrict__ W2,
    const float* __restrict__ att_s, const float* __restrict__ att_d,
    float* __restrict__ h2, float* __restrict__ as2, float* __restrict__ ad2)
{
  __shared__ float W2s[OUT_CH * 512];
  int t = threadIdx.x;
  for (int i = t * 4; i < OUT_CH * 512; i += 1024)
    *(float4*)&W2s[i] = *(const float4*)&W2[i];
  __syncthreads();
  int wave = t >> 6, lane = t & 63;
  int n = blockIdx.x * 4 + wave;   // grid = N/4 exactly
  const float* xr = in + (size_t)n * 512;
  float acc[16] = {};
  for (int k = lane; k < 512; k += 64) {
    float xv = xr[k];
#pragma unroll
    for (int j = 0; j < 16; j++) acc[j] = fmaf(xv, W2s[j * 512 + k], acc[j]);
  }
#pragma unroll
  for (int j = 0; j < 16; j++)
#pragma unroll
    for (int off = 32; off; off >>= 1) acc[j] += __shfl_xor(acc[j], off);
  if (lane == 0) {
    float s = 0.f, dd = 0.f;
#pragma unroll
    for (int j = 0; j < 16; j++) {
      h2[(size_t)n * 16 + j] = acc[j];
      s  = fmaf(acc[j], att_s[j], s);
      dd = fmaf(acc[j], att_d[j], dd);
    }
    as2[n] = s; ad2[n] = dd;
  }
}

// ------- layer-2 softmax + aggregate (one wave per dst), fused +b2 ----------
__global__ __launch_bounds__(256) void agg2_kernel(
    const int* __restrict__ row, const int* __restrict__ csr,
    const float* __restrict__ h2, const float* __restrict__ as2,
    const float* __restrict__ ad2, const float* __restrict__ b2,
    float* __restrict__ out)
{
  int wave = threadIdx.x >> 6, lane = threadIdx.x & 63;
  int d = blockIdx.x * 4 + wave;   // grid = N/4 exactly
  int beg = row[d], end = row[d + 1];
  float add = ad2[d];

  float m = -1e30f;
  for (int e = beg + lane; e < end; e += 64) {
    float v = as2[csr[e]] + add;
    v = (v >= 0.f) ? v : NEG * v;
    m = fmaxf(m, v);
  }
#pragma unroll
  for (int off = 32; off; off >>= 1) m = fmaxf(m, __shfl_xor(m, off));
  float z = 0.f;
  for (int e = beg + lane; e < end; e += 64) {
    float v = as2[csr[e]] + add;
    v = (v >= 0.f) ? v : NEG * v;
    z += __expf(v - m);
  }
#pragma unroll
  for (int off = 32; off; off >>= 1) z += __shfl_xor(z, off);

  int c = lane & 15;
  float acc = 0.f;
  for (int e = beg + (lane >> 4); e < end; e += 4) {
    int s = csr[e];
    float v = as2[s] + add;
    v = (v >= 0.f) ? v : NEG * v;
    float al = __expf(v - m) / z;
    acc = fmaf(al, h2[(size_t)s * 16 + c], acc);
  }
  acc += __shfl_xor(acc, 16);
  acc += __shfl_xor(acc, 32);
  if (lane < 16) out[(size_t)d * 16 + lane] = acc + b2[lane];
}

extern "C" void kernel_launch(void* const* d_in, const int* in_sizes, int n_in,
                              void* d_out, int out_size, void* d_ws, size_t ws_size,
                              hipStream_t stream)
{
  const float* x    = (const float*)d_in[0];
  const int*   ei   = (const int*)d_in[1];
  const float* W1   = (const float*)d_in[2];
  const float* asv1 = (const float*)d_in[3];
  const float* adv1 = (const float*)d_in[4];
  const float* b1   = (const float*)d_in[5];
  const float* W2   = (const float*)d_in[6];
  const float* asv2 = (const float*)d_in[7];
  const float* adv2 = (const float*)d_in[8];
  const float* b2   = (const float*)d_in[9];
  float* out = (float*)d_out;

  // workspace layout (16B-aligned regions)
  unsigned short* h1b = (unsigned short*)d_ws;               // N*512 bf16
  float* relu1 = (float*)(h1b + (size_t)Nn * C1);            // N*512 f32 (aliased x_hi/x_lo pre-agg1)
  float* as1   = relu1 + (size_t)Nn * C1;                    // N*8
  float* ad1   = as1 + (size_t)Nn * H1n;                     // N*8
  float* h2    = ad1 + (size_t)Nn * H1n;                     // N*16
  float* as2   = h2 + (size_t)Nn * OUT_CH;                   // N
  float* ad2   = as2 + Nn;                                   // N
  int* csr  = (int*)(ad2 + Nn);                              // E+N (aliased W_hi/W_lo pre-scatter)
  int* cnt  = csr + EPn;                                     // N
  int* rowp = cnt + Nn;                                      // N+1
  int* cur  = rowp + Nn + 1;                                 // N

  unsigned short* x_hi = (unsigned short*)relu1;             // N*512 bf16
  unsigned short* x_lo = x_hi + (size_t)Nn * IN_CH;          // N*512 bf16
  unsigned short* w_hi = (unsigned short*)csr;               // 512*512 bf16
  unsigned short* w_lo = w_hi + (size_t)C1 * IN_CH;          // 512*512 bf16

  hipMemsetAsync(cnt, 0, Nn * sizeof(int), stream);
  hipMemsetAsync(cur, 0, Nn * sizeof(int), stream);

  split_kernel<<<(Nn * IN_CH / 8 + 255) / 256, 256, 0, stream>>>(x, x_hi, x_lo, Nn * IN_CH / 8);
  split_kernel<<<(C1 * IN_CH / 8 + 255) / 256, 256, 0, stream>>>(W1, w_hi, w_lo, C1 * IN_CH / 8);

  dim3 g1(157, 4);
  gemm1_mfma<<<g1, 256, 0, stream>>>(x_hi, x_lo, w_hi, w_lo, h1b);

  logits1_kernel<<<(Nn * H1n) / 4, 256, 0, stream>>>(h1b, asv1, adv1, as1, ad1);
  hist_kernel<<<(EPn + 255) / 256, 256, 0, stream>>>(ei, cnt);
  scan_kernel<<<1, 1024, 0, stream>>>(cnt, rowp);
  scatter_kernel<<<(EPn + 255) / 256, 256, 0, stream>>>(ei, rowp, cur, csr);  // overwrites w_hi/w_lo (gemm done)
  agg1_kernel<<<Nn, 256, 0, stream>>>(rowp, csr, h1b, as1, ad1, b1, relu1);   // overwrites x_hi/x_lo (gemm done)
  l2_kernel<<<Nn / 4, 256, 0, stream>>>(relu1, W2, asv2, adv2, h2, as2, ad2);
  agg2_kernel<<<Nn / 4, 256, 0, stream>>>(rowp, csr, h2, as2, ad2, b2, out);
}

// Round 5
// 267.972 us; speedup vs baseline: 1.5843x; 1.1179x over previous
//
#include <hip/hip_runtime.h>

#define Nn     20000
#define IN_CH  512
#define C1     512      // H1*HID
#define H1n    8
#define HIDn   64
#define OUT_CH 16
#define En     320000
#define EPn    340000   // E + N self-loops
#define NEG    0.2f

typedef __attribute__((ext_vector_type(8))) short bf16x8;
typedef __attribute__((ext_vector_type(4))) float f32x4;

// ---------------- fp32 -> bf16 helpers (RNE) --------------------------------
__device__ inline unsigned short bf16_rne(float f) {
  unsigned int u = __float_as_uint(f);
  return (unsigned short)((u + 0x7fffu + ((u >> 16) & 1u)) >> 16);
}
__device__ inline float bf16_f(unsigned short u) {
  return __uint_as_float(((unsigned int)u) << 16);
}

// x -> bf16 (hi only)
__global__ __launch_bounds__(256) void cvt_kernel(
    const float* __restrict__ in, unsigned short* __restrict__ outb, int n8)
{
  int i = blockIdx.x * 256 + threadIdx.x;
  if (i >= n8) return;
  float4 f0 = ((const float4*)in)[i * 2];
  float4 f1 = ((const float4*)in)[i * 2 + 1];
  float f[8] = {f0.x, f0.y, f0.z, f0.w, f1.x, f1.y, f1.z, f1.w};
  unsigned short h[8];
#pragma unroll
  for (int j = 0; j < 8; j++) h[j] = bf16_rne(f[j]);
  ushort4 hv0 = {h[0], h[1], h[2], h[3]}, hv1 = {h[4], h[5], h[6], h[7]};
  ((ushort4*)outb)[i * 2] = hv0; ((ushort4*)outb)[i * 2 + 1] = hv1;
}

// W -> (hi, lo) bf16 split
__global__ __launch_bounds__(256) void split_kernel(
    const float* __restrict__ in, unsigned short* __restrict__ hi,
    unsigned short* __restrict__ lo, int n8)
{
  int i = blockIdx.x * 256 + threadIdx.x;
  if (i >= n8) return;
  float4 f0 = ((const float4*)in)[i * 2];
  float4 f1 = ((const float4*)in)[i * 2 + 1];
  float f[8] = {f0.x, f0.y, f0.z, f0.w, f1.x, f1.y, f1.z, f1.w};
  unsigned short h[8], l[8];
#pragma unroll
  for (int j = 0; j < 8; j++) {
    unsigned short hb = bf16_rne(f[j]);
    h[j] = hb;
    l[j] = bf16_rne(f[j] - bf16_f(hb));
  }
  ushort4 hv0 = {h[0], h[1], h[2], h[3]}, hv1 = {h[4], h[5], h[6], h[7]};
  ushort4 lv0 = {l[0], l[1], l[2], l[3]}, lv1 = {l[4], l[5], l[6], l[7]};
  ((ushort4*)hi)[i * 2] = hv0; ((ushort4*)hi)[i * 2 + 1] = hv1;
  ((ushort4*)lo)[i * 2] = lv0; ((ushort4*)lo)[i * 2 + 1] = lv1;
}

// ------ GEMM1 (2-term split MFMA): h1b[N,512](bf16) = x @ W1^T --------------
#define GLL(gp, lp) __builtin_amdgcn_global_load_lds( \
    (const __attribute__((address_space(1))) void*)(gp), \
    (__attribute__((address_space(3))) void*)(lp), 16, 0, 0)

// involutive chunk swizzle: spreads 64B-stride rows across all 8 bank groups
#define SWZ(c) ((c) ^ (((c) >> 3) & 3))

__global__ __launch_bounds__(256, 2) void gemm1_mfma(
    const unsigned short* __restrict__ Ab,
    const unsigned short* __restrict__ Bhi, const unsigned short* __restrict__ Blo,
    unsigned short* __restrict__ Cb)
{
  __shared__ unsigned short sA[128 * 32];
  __shared__ unsigned short sBhi[128 * 32], sBlo[128 * 32];
  int t = threadIdx.x;
  int bm = blockIdx.x, bn = blockIdx.y;
  int lane = t & 63, w = t >> 6;

  // staging: 512 16B-chunks per tile; LDS slot q holds tile-chunk SWZ(q)
  int slot0 = w * 128 + lane;
  int slot1 = slot0 + 64;
  int cb0 = w * 128, cb1 = w * 128 + 64;     // wave-uniform LDS base chunks
  int cs0 = SWZ(slot0), cs1 = SWZ(slot1);    // tile-chunk fetched by this lane
  int ar0 = bm * 128 + (cs0 >> 2); if (ar0 > Nn - 1) ar0 = Nn - 1;
  int ar1 = bm * 128 + (cs1 >> 2); if (ar1 > Nn - 1) ar1 = Nn - 1;
  int br0 = bn * 128 + (cs0 >> 2);
  int br1 = bn * 128 + (cs1 >> 2);
  size_t offA0 = (size_t)ar0 * IN_CH + (cs0 & 3) * 8;
  size_t offA1 = (size_t)ar1 * IN_CH + (cs1 & 3) * 8;
  size_t offB0 = (size_t)br0 * IN_CH + (cs0 & 3) * 8;
  size_t offB1 = (size_t)br1 * IN_CH + (cs1 & 3) * 8;

  int wm = (w >> 1) * 64, wn = (w & 1) * 64;
  int lr = lane & 15, kb = lane >> 4;

  f32x4 acc[4][4] = {};

  for (int k0 = 0; k0 < IN_CH; k0 += 32) {
    __syncthreads();                      // prev iter's LDS reads done
    GLL(Ab  + offA0 + k0, sA   + cb0 * 8);
    GLL(Ab  + offA1 + k0, sA   + cb1 * 8);
    GLL(Bhi + offB0 + k0, sBhi + cb0 * 8);
    GLL(Bhi + offB1 + k0, sBhi + cb1 * 8);
    GLL(Blo + offB0 + k0, sBlo + cb0 * 8);
    GLL(Blo + offB1 + k0, sBlo + cb1 * 8);
    __syncthreads();                      // loads landed

    bf16x8 ah[4], bh[4], bl[4];
#pragma unroll
    for (int i = 0; i < 4; i++) {
      int rca = (wm + i * 16 + lr) * 4 + kb;
      int sca = SWZ(rca);
      ah[i] = *(const bf16x8*)&sA[sca * 8];
      int rcb = (wn + i * 16 + lr) * 4 + kb;
      int scb = SWZ(rcb);
      bh[i] = *(const bf16x8*)&sBhi[scb * 8];
      bl[i] = *(const bf16x8*)&sBlo[scb * 8];
    }
#pragma unroll
    for (int i = 0; i < 4; i++)
#pragma unroll
      for (int j = 0; j < 4; j++) {
        acc[i][j] = __builtin_amdgcn_mfma_f32_16x16x32_bf16(ah[i], bh[j], acc[i][j], 0, 0, 0);
        acc[i][j] = __builtin_amdgcn_mfma_f32_16x16x32_bf16(ah[i], bl[j], acc[i][j], 0, 0, 0);
      }
  }

  int lq = lane >> 4;
#pragma unroll
  for (int i = 0; i < 4; i++) {
    int r0 = bm * 128 + wm + i * 16 + lq * 4;
#pragma unroll
    for (int j = 0; j < 4; j++) {
      int cc = bn * 128 + wn + j * 16 + lr;
#pragma unroll
      for (int q = 0; q < 4; q++) {
        int r = r0 + q;
        if (r < Nn) Cb[(size_t)r * C1 + cc] = bf16_rne(acc[i][j][q]);
      }
    }
  }
}

// ------------- per-(node,head) attention logits from bf16 h1 ----------------
__global__ __launch_bounds__(256) void logits1_kernel(
    const unsigned short* __restrict__ h1b, const float* __restrict__ att_s,
    const float* __restrict__ att_d, float* __restrict__ as1, float* __restrict__ ad1)
{
  int wave = threadIdx.x >> 6, lane = threadIdx.x & 63;
  int p = blockIdx.x * 4 + wave;            // pair index n*8+h
  if (p >= Nn * H1n) return;
  int n = p >> 3, h = p & 7;
  float v = bf16_f(h1b[(size_t)n * C1 + h * HIDn + lane]);
  float s = v * att_s[h * HIDn + lane];
  float d = v * att_d[h * HIDn + lane];
#pragma unroll
  for (int off = 32; off; off >>= 1) {
    s += __shfl_xor(s, off);
    d += __shfl_xor(d, off);
  }
  if (lane == 0) { as1[p] = s; ad1[p] = d; }
}

// --------------------------- CSR build by dst -------------------------------
__global__ void hist_kernel(const int* __restrict__ ei, int* __restrict__ cnt)
{
  int e = blockIdx.x * 256 + threadIdx.x;
  if (e >= EPn) return;
  int d = (e < En) ? ei[En + e] : (e - En);
  atomicAdd(&cnt[d], 1);
}

__global__ __launch_bounds__(1024) void scan_kernel(
    const int* __restrict__ cnt, int* __restrict__ row)
{
  __shared__ int wsum[16];
  int t = threadIdx.x;
  int base = t * 20;
  int v[20];
  int s = 0;
#pragma unroll
  for (int j = 0; j < 20; j++) {
    int i = base + j;
    int c = (i < Nn) ? cnt[i] : 0;
    v[j] = s;
    s += c;
  }
  int lane = t & 63, w = t >> 6;
  int incl = s;
#pragma unroll
  for (int off = 1; off < 64; off <<= 1) {
    int o = __shfl_up(incl, off);
    if (lane >= off) incl += o;
  }
  if (lane == 63) wsum[w] = incl;
  __syncthreads();
  if (w == 0) {
    int ws = (lane < 16) ? wsum[lane] : 0;
#pragma unroll
    for (int off = 1; off < 16; off <<= 1) {
      int o = __shfl_up(ws, off);
      if (lane >= off) ws += o;
    }
    if (lane < 16) wsum[lane] = ws;
  }
  __syncthreads();
  int excl = ((w > 0) ? wsum[w - 1] : 0) + incl - s;
#pragma unroll
  for (int j = 0; j < 20; j++) {
    int i = base + j;
    if (i < Nn) row[i] = excl + v[j];
  }
  if (t == 0) row[Nn] = EPn;
}

__global__ void scatter_kernel(const int* __restrict__ ei, const int* __restrict__ row,
                               int* __restrict__ cur, int* __restrict__ csr)
{
  int e = blockIdx.x * 256 + threadIdx.x;
  if (e >= EPn) return;
  int s, d;
  if (e < En) { s = ei[e]; d = ei[En + e]; }
  else        { s = e - En; d = e - En; }
  int pos = row[d] + atomicAdd(&cur[d], 1);
  csr[pos] = s;
}

// ----- layer-1 softmax + aggregate (block per dst) --------------------------
// Wave pair (w>>1) owns heads [4*(w>>1), +4) = channels [256*(w>>1), +256);
// the two waves of a pair split edges by parity.  Alpha for a 16-edge chunk is
// computed once per (edge,head) and staged in the wave's PRIVATE LDS slice
// (within-wave ds ordering, no barrier).  Single write-once/barrier/read
// combine of the two parity partials at the end.
__global__ __launch_bounds__(256) void agg1_kernel(
    const int* __restrict__ row, const int* __restrict__ csr,
    const unsigned short* __restrict__ h1b, const float* __restrict__ as1,
    const float* __restrict__ adv, const float* __restrict__ b1,
    float* __restrict__ out)
{
  __shared__ int   wsrc[4][16];
  __shared__ float walpha[4][16][4];
  __shared__ float part[2][64][4];

  int d = blockIdx.x;
  int beg = row[d], end = row[d + 1];
  int t = threadIdx.x, lane = t & 63, w = t >> 6;
  int hset = (w >> 1) * 4;              // this wave's 4 heads
  int p = w & 1;                        // edge parity this wave consumes
  float4 adp = *(const float4*)&adv[d * 8 + hset];

  // pass 1: per-head max over all edges (pair waves duplicate this cheap pass)
  float m0 = -1e30f, m1 = -1e30f, m2 = -1e30f, m3 = -1e30f;
  for (int e = beg + lane; e < end; e += 64) {
    int s = csr[e];
    float4 a = *(const float4*)&as1[s * 8 + hset];
    float v0 = a.x + adp.x; v0 = v0 >= 0.f ? v0 : NEG * v0; m0 = fmaxf(m0, v0);
    float v1 = a.y + adp.y; v1 = v1 >= 0.f ? v1 : NEG * v1; m1 = fmaxf(m1, v1);
    float v2 = a.z + adp.z; v2 = v2 >= 0.f ? v2 : NEG * v2; m2 = fmaxf(m2, v2);
    float v3 = a.w + adp.w; v3 = v3 >= 0.f ? v3 : NEG * v3; m3 = fmaxf(m3, v3);
  }
#pragma unroll
  for (int off = 32; off; off >>= 1) {
    m0 = fmaxf(m0, __shfl_xor(m0, off)); m1 = fmaxf(m1, __shfl_xor(m1, off));
    m2 = fmaxf(m2, __shfl_xor(m2, off)); m3 = fmaxf(m3, __shfl_xor(m3, off));
  }
  // pass 2: per-head denominator
  float z0 = 0.f, z1 = 0.f, z2 = 0.f, z3 = 0.f;
  for (int e = beg + lane; e < end; e += 64) {
    int s = csr[e];
    float4 a = *(const float4*)&as1[s * 8 + hset];
    float v0 = a.x + adp.x; v0 = v0 >= 0.f ? v0 : NEG * v0; z0 += __expf(v0 - m0);
    float v1 = a.y + adp.y; v1 = v1 >= 0.f ? v1 : NEG * v1; z1 += __expf(v1 - m1);
    float v2 = a.z + adp.z; v2 = v2 >= 0.f ? v2 : NEG * v2; z2 += __expf(v2 - m2);
    float v3 = a.w + adp.w; v3 = v3 >= 0.f ? v3 : NEG * v3; z3 += __expf(v3 - m3);
  }
#pragma unroll
  for (int off = 32; off; off >>= 1) {
    z0 += __shfl_xor(z0, off); z1 += __shfl_xor(z1, off);
    z2 += __shfl_xor(z2, off); z3 += __shfl_xor(z3, off);
  }

  // per-lane head constants (static selection, no register indexing)
  int hq = lane >> 4;
  float mH  = hq == 0 ? m0 : hq == 1 ? m1 : hq == 2 ? m2 : m3;
  float zH  = hq == 0 ? z0 : hq == 1 ? z1 : hq == 2 ? z2 : z3;
  float adH = hq == 0 ? adp.x : hq == 1 ? adp.y : hq == 2 ? adp.z : adp.w;
  float rzH = 1.f / zH;

  int deg = end - beg;
  int nj  = (deg - p + 1) >> 1;         // # edges with index parity p
  int li  = lane & 15;
  size_t chb = (size_t)256 * (w >> 1) + 4 * lane;   // channel base (4 ch/lane)

  float a0 = 0.f, a1 = 0.f, a2 = 0.f, a3 = 0.f;
  for (int jb = 0; jb < nj; jb += 16) {
    int cnt = min(16, nj - jb);
    int jj = jb + li;
    if (jj < nj) {
      int s = csr[beg + p + 2 * jj];
      if (hq == 0) wsrc[w][li] = s;     // single writer per slot
      float v = as1[s * 8 + hset + hq] + adH;
      v = v >= 0.f ? v : NEG * v;
      walpha[w][li][hq] = __expf(v - mH) * rzH;   // single writer per slot
    }
    // within-wave ds_write -> ds_read: ordered by lgkmcnt, no barrier needed
    for (int i = 0; i < cnt; i++) {
      int s = wsrc[w][i];
      float al = walpha[w][i][hq];
      uint2 u = *(const uint2*)&h1b[(size_t)s * C1 + chb];
      a0 = fmaf(al, __uint_as_float(u.x << 16), a0);
      a1 = fmaf(al, __uint_as_float(u.x & 0xffff0000u), a1);
      a2 = fmaf(al, __uint_as_float(u.y << 16), a2);
      a3 = fmaf(al, __uint_as_float(u.y & 0xffff0000u), a3);
    }
  }

  // combine the two parity partials (write-once slots, one barrier)
  if (p == 1) {
    part[w >> 1][lane][0] = a0; part[w >> 1][lane][1] = a1;
    part[w >> 1][lane][2] = a2; part[w >> 1][lane][3] = a3;
  }
  __syncthreads();
  if (p == 0) {
    a0 += part[w >> 1][lane][0]; a1 += part[w >> 1][lane][1];
    a2 += part[w >> 1][lane][2]; a3 += part[w >> 1][lane][3];
    float4 bb = *(const float4*)&b1[chb];
    float o0 = a0 + bb.x, o1 = a1 + bb.y, o2 = a2 + bb.z, o3 = a3 + bb.w;
    float4 o = {o0 > 0.f ? o0 : 0.f, o1 > 0.f ? o1 : 0.f,
                o2 > 0.f ? o2 : 0.f, o3 > 0.f ? o3 : 0.f};
    *(float4*)&out[(size_t)d * C1 + chb] = o;
  }
}

// --------- layer-2 transform: h2[N,16] = relu1 @ W2^T; a_s2, a_d2 -----------
__global__ __launch_bounds__(256) void l2_kernel(
    const float* __restrict__ in, const float* __restrict__ W2,
    const float* __restrict__ att_s, const float* __restrict__ att_d,
    float* __restrict__ h2, float* __restrict__ as2, float* __restrict__ ad2)
{
  __shared__ float W2s[OUT_CH * 512];
  int t = threadIdx.x;
  for (int i = t * 4; i < OUT_CH * 512; i += 1024)
    *(float4*)&W2s[i] = *(const float4*)&W2[i];
  __syncthreads();
  int wave = t >> 6, lane = t & 63;
  int n = blockIdx.x * 4 + wave;   // grid = N/4 exactly
  const float* xr = in + (size_t)n * 512;
  float acc[16] = {};
  for (int k = lane; k < 512; k += 64) {
    float xv = xr[k];
#pragma unroll
    for (int j = 0; j < 16; j++) acc[j] = fmaf(xv, W2s[j * 512 + k], acc[j]);
  }
#pragma unroll
  for (int j = 0; j < 16; j++)
#pragma unroll
    for (int off = 32; off; off >>= 1) acc[j] += __shfl_xor(acc[j], off);
  if (lane == 0) {
    float s = 0.f, dd = 0.f;
#pragma unroll
    for (int j = 0; j < 16; j++) {
      h2[(size_t)n * 16 + j] = acc[j];
      s  = fmaf(acc[j], att_s[j], s);
      dd = fmaf(acc[j], att_d[j], dd);
    }
    as2[n] = s; ad2[n] = dd;
  }
}

// ------- layer-2 softmax + aggregate (one wave per dst), fused +b2 ----------
__global__ __launch_bounds__(256) void agg2_kernel(
    const int* __restrict__ row, const int* __restrict__ csr,
    const float* __restrict__ h2, const float* __restrict__ as2,
    const float* __restrict__ ad2, const float* __restrict__ b2,
    float* __restrict__ out)
{
  int wave = threadIdx.x >> 6, lane = threadIdx.x & 63;
  int d = blockIdx.x * 4 + wave;   // grid = N/4 exactly
  int beg = row[d], end = row[d + 1];
  float add = ad2[d];

  float m = -1e30f;
  for (int e = beg + lane; e < end; e += 64) {
    float v = as2[csr[e]] + add;
    v = (v >= 0.f) ? v : NEG * v;
    m = fmaxf(m, v);
  }
#pragma unroll
  for (int off = 32; off; off >>= 1) m = fmaxf(m, __shfl_xor(m, off));
  float z = 0.f;
  for (int e = beg + lane; e < end; e += 64) {
    float v = as2[csr[e]] + add;
    v = (v >= 0.f) ? v : NEG * v;
    z += __expf(v - m);
  }
#pragma unroll
  for (int off = 32; off; off >>= 1) z += __shfl_xor(z, off);

  int c = lane & 15;
  float acc = 0.f;
  for (int e = beg + (lane >> 4); e < end; e += 4) {
    int s = csr[e];
    float v = as2[s] + add;
    v = (v >= 0.f) ? v : NEG * v;
    float al = __expf(v - m) / z;
    acc = fmaf(al, h2[(size_t)s * 16 + c], acc);
  }
  acc += __shfl_xor(acc, 16);
  acc += __shfl_xor(acc, 32);
  if (lane < 16) out[(size_t)d * 16 + lane] = acc + b2[lane];
}

extern "C" void kernel_launch(void* const* d_in, const int* in_sizes, int n_in,
                              void* d_out, int out_size, void* d_ws, size_t ws_size,
                              hipStream_t stream)
{
  const float* x    = (const float*)d_in[0];
  const int*   ei   = (const int*)d_in[1];
  const float* W1   = (const float*)d_in[2];
  const float* asv1 = (const float*)d_in[3];
  const float* adv1 = (const float*)d_in[4];
  const float* b1   = (const float*)d_in[5];
  const float* W2   = (const float*)d_in[6];
  const float* asv2 = (const float*)d_in[7];
  const float* adv2 = (const float*)d_in[8];
  const float* b2   = (const float*)d_in[9];
  float* out = (float*)d_out;

  // workspace layout (16B-aligned regions)
  unsigned short* h1b = (unsigned short*)d_ws;               // N*512 bf16
  float* relu1 = (float*)(h1b + (size_t)Nn * C1);            // N*512 f32 (aliased x_b pre-agg1)
  float* as1   = relu1 + (size_t)Nn * C1;                    // N*8
  float* ad1   = as1 + (size_t)Nn * H1n;                     // N*8
  float* h2    = ad1 + (size_t)Nn * H1n;                     // N*16
  float* as2   = h2 + (size_t)Nn * OUT_CH;                   // N
  float* ad2   = as2 + Nn;                                   // N
  int* csr  = (int*)(ad2 + Nn);                              // E+N (aliased W_hi/W_lo pre-scatter)
  int* cnt  = csr + EPn;                                     // N
  int* rowp = cnt + Nn;                                      // N+1
  int* cur  = rowp + Nn + 1;                                 // N

  unsigned short* x_b  = (unsigned short*)relu1;             // N*512 bf16
  unsigned short* w_hi = (unsigned short*)csr;               // 512*512 bf16
  unsigned short* w_lo = w_hi + (size_t)C1 * IN_CH;          // 512*512 bf16

  hipMemsetAsync(cnt, 0, Nn * sizeof(int), stream);
  hipMemsetAsync(cur, 0, Nn * sizeof(int), stream);

  cvt_kernel<<<(Nn * IN_CH / 8 + 255) / 256, 256, 0, stream>>>(x, x_b, Nn * IN_CH / 8);
  split_kernel<<<(C1 * IN_CH / 8 + 255) / 256, 256, 0, stream>>>(W1, w_hi, w_lo, C1 * IN_CH / 8);

  dim3 g1(157, 4);
  gemm1_mfma<<<g1, 256, 0, stream>>>(x_b, w_hi, w_lo, h1b);

  logits1_kernel<<<(Nn * H1n) / 4, 256, 0, stream>>>(h1b, asv1, adv1, as1, ad1);
  hist_kernel<<<(EPn + 255) / 256, 256, 0, stream>>>(ei, cnt);
  scan_kernel<<<1, 1024, 0, stream>>>(cnt, rowp);
  scatter_kernel<<<(EPn + 255) / 256, 256, 0, stream>>>(ei, rowp, cur, csr);  // overwrites w_hi/w_lo (gemm done)
  agg1_kernel<<<Nn, 256, 0, stream>>>(rowp, csr, h1b, as1, ad1, b1, relu1);   // overwrites x_b (gemm done)
  l2_kernel<<<Nn / 4, 256, 0, stream>>>(relu1, W2, asv2, adv2, h2, as2, ad2);
  agg2_kernel<<<Nn / 4, 256, 0, stream>>>(rowp, csr, h2, as2, ad2, b2, out);
}